// Round 11
// baseline (222.422 us; speedup 1.0000x reference)
//
#include <hip/hip_runtime.h>
#include <hip/hip_cooperative_groups.h>
#include <hip/hip_bf16.h>
#include <math.h>

namespace cg = cooperative_groups;

typedef short short8 __attribute__((ext_vector_type(8)));
typedef float f32x4 __attribute__((ext_vector_type(4)));

#define NROW 4096
#define DIM  128
#define NCLS 64
#define MAXM 128
#define LCAP 256
#define NBT  64      // 64 row-blocks of 64 rows
#define NTILE 2080   // NBT*(NBT+1)/2 upper-tri 64x64 tiles
#define PS   66      // per-row partial-slot stride (65 slots used)

typedef __attribute__((address_space(3))) unsigned lds_u32;
typedef const __attribute__((address_space(1))) unsigned glb_u32;

__device__ __forceinline__ void gload16(const void* g, void* lds) {
    __builtin_amdgcn_global_load_lds((glb_u32*)g, (lds_u32*)lds, 16, 0, 0);
}

__device__ __forceinline__ unsigned short f2bf(float f) {
    unsigned u = __builtin_bit_cast(unsigned, f);
    unsigned r = (u + 0x7fffu + ((u >> 16) & 1u)) >> 16;   // RNE
    return (unsigned short)r;
}

// ======================= shared bodies (used by both paths) =======================

__device__ __forceinline__ void prep_rows(const float* __restrict__ X,
        unsigned short* __restrict__ Xb, float* __restrict__ sq, int row0, int t)
{
    int row = row0 + (t >> 5);
    int c = t & 31;
    float4 v = *reinterpret_cast<const float4*>(X + (size_t)row * DIM + c * 4);
    float p = v.x * v.x + v.y * v.y + v.z * v.z + v.w * v.w;
    p += __shfl_xor(p, 16, 32);
    p += __shfl_xor(p, 8, 32);
    p += __shfl_xor(p, 4, 32);
    p += __shfl_xor(p, 2, 32);
    p += __shfl_xor(p, 1, 32);
    ushort4 h;
    h.x = f2bf(v.x); h.y = f2bf(v.y); h.z = f2bf(v.z); h.w = f2bf(v.w);
    *reinterpret_cast<ushort4*>(Xb + (size_t)row * DIM + c * 4) = h;
    if (c == 0) sq[row] = p;
}

struct SRow {
    unsigned short tA[64 * 128];
    unsigned short tB[64 * 128];
    float sqi[64], sqj[64], cacc[4][64];
    int   ti[64], tj[64];
};
struct SLoss {
    unsigned short tX[MAXM * DIM];
    float sqg[MAXM], rng[MAXM];
    int   idx[LCAP], wsum[4];
    float red[16];
};

// rowneg tile body: computes P partials for triangular tile k
template <typename SM>
__device__ __forceinline__ void rowneg_tile(SM* smp,
        const unsigned short* __restrict__ Xb, const float* __restrict__ sq,
        const int* __restrict__ tgt, float* __restrict__ P, int k, int t)
{
    SRow& sm = smp->r;
    const int w = t >> 6, l = t & 63, lr = l & 15, lg = l >> 4;

    int bi = (int)(64.5f - sqrtf(64.5f * 64.5f - 2.0f * (float)k));
    if (bi < 0) bi = 0; if (bi > NBT - 1) bi = NBT - 1;
    while (bi < NBT - 1 && ((bi + 1) * NBT - (((bi + 1) * bi) >> 1)) <= k) ++bi;
    while (bi > 0 && (bi * NBT - ((bi * (bi - 1)) >> 1)) > k) --bi;
    const int bj = bi + (k - (bi * NBT - ((bi * (bi - 1)) >> 1)));
    const int gib = bi * 64, gjb = bj * 64;
    const bool diag = (bi == bj);

    #pragma unroll
    for (int kk = 0; kk < 4; ++kk) {
        int q = w * 4 + kk;
        int row = q * 4 + (l >> 4);
        int sc = (l & 15) ^ (row & 7);
        gload16(Xb + (size_t)(gib + row) * DIM + sc * 8, &sm.tA[q * 512]);
        if (!diag)
            gload16(Xb + (size_t)(gjb + row) * DIM + sc * 8, &sm.tB[q * 512]);
    }
    if (t < 64)       { sm.sqi[t] = sq[gib + t]; sm.ti[t] = tgt[gib + t]; }
    else if (t < 128) { int u = t - 64; sm.sqj[u] = sq[gjb + u]; sm.tj[u] = tgt[gjb + u]; }
    __syncthreads();

    const unsigned short* tBp = diag ? sm.tA : sm.tB;
    const int arow = w * 16 + lr;

    f32x4 C[4] = {};
    #pragma unroll
    for (int ks = 0; ks < 4; ++ks) {
        int c = ks * 4 + lg;
        short8 a = *reinterpret_cast<const short8*>(&sm.tA[arow * 128 + ((c ^ (arow & 7)) * 8)]);
        #pragma unroll
        for (int fj = 0; fj < 4; ++fj) {
            int brow = fj * 16 + lr;
            short8 bb = *reinterpret_cast<const short8*>(&tBp[brow * 128 + ((c ^ (brow & 7)) * 8)]);
            C[fj] = __builtin_amdgcn_mfma_f32_16x16x32_bf16(a, bb, C[fj], 0, 0, 0);
        }
    }

    const int ibase = w * 16 + lg * 4;
    float sqi[4]; int ti[4];
    #pragma unroll
    for (int r = 0; r < 4; ++r) { sqi[r] = sm.sqi[ibase + r]; ti[r] = sm.ti[ibase + r]; }

    float racc[4] = {0.f, 0.f, 0.f, 0.f};
    float cacc[4] = {0.f, 0.f, 0.f, 0.f};
    #pragma unroll
    for (int fj = 0; fj < 4; ++fj) {
        int jl = fj * 16 + lr;
        float sqj = sm.sqj[jl];
        int   tj  = sm.tj[jl];
        int   gj  = gjb + jl;
        #pragma unroll
        for (int r = 0; r < 4; ++r) {
            int gi = gib + ibase + r;
            float d2 = fmaxf(sqi[r] + sqj - 2.0f * C[fj][r], 0.0f);
            float dist = __builtin_amdgcn_sqrtf(d2);
            float e = __expf(1.0f - dist);
            bool valid = (gi < gj) && (ti[r] != tj) && (d2 > 0.0f);
            e = valid ? e : 0.0f;
            racc[r] += e;
            cacc[fj] += e;
        }
    }

    #pragma unroll
    for (int r = 0; r < 4; ++r) {
        racc[r] += __shfl_xor(racc[r], 1);
        racc[r] += __shfl_xor(racc[r], 2);
        racc[r] += __shfl_xor(racc[r], 4);
        racc[r] += __shfl_xor(racc[r], 8);
    }
    if (lr == 0) {
        #pragma unroll
        for (int r = 0; r < 4; ++r)
            P[(size_t)(gib + ibase + r) * PS + (bj + 1)] = racc[r];
    }
    #pragma unroll
    for (int fj = 0; fj < 4; ++fj) {
        cacc[fj] += __shfl_xor(cacc[fj], 16);
        cacc[fj] += __shfl_xor(cacc[fj], 32);
    }
    if (lg == 0) {
        #pragma unroll
        for (int fj = 0; fj < 4; ++fj) sm.cacc[w][fj * 16 + lr] = cacc[fj];
    }
    __syncthreads();
    if (t < 64) {
        float cs = sm.cacc[0][t] + sm.cacc[1][t] + sm.cacc[2][t] + sm.cacc[3][t];
        P[(size_t)(gjb + t) * PS + bi] = cs;
    }
}

// loss body for (class c, half h): accumulates into acc via atomicAdd
template <typename SM>
__device__ __forceinline__ void loss_body(SM* smp,
        const unsigned short* __restrict__ Xb, const float* __restrict__ X,
        const float* __restrict__ sq, const int* __restrict__ tgt,
        const float* __restrict__ P, float* __restrict__ acc, int c, int h, int t)
{
    SLoss& sm = smp->l;
    const int w = t >> 6, l = t & 63, lr = l & 15, lg = l >> 4;

    float csum = 0.0f, cpairs = 0.0f;
    int mtot, mm, nfj;

    {
        const int rbase = t * 16;
        int tv[16];
        {
            int4 a = *reinterpret_cast<const int4*>(tgt + rbase);
            int4 b = *reinterpret_cast<const int4*>(tgt + rbase + 4);
            int4 d = *reinterpret_cast<const int4*>(tgt + rbase + 8);
            int4 e = *reinterpret_cast<const int4*>(tgt + rbase + 12);
            tv[0]=a.x; tv[1]=a.y; tv[2]=a.z; tv[3]=a.w;
            tv[4]=b.x; tv[5]=b.y; tv[6]=b.z; tv[7]=b.w;
            tv[8]=d.x; tv[9]=d.y; tv[10]=d.z; tv[11]=d.w;
            tv[12]=e.x; tv[13]=e.y; tv[14]=e.z; tv[15]=e.w;
        }
        int cnt = 0;
        #pragma unroll
        for (int k2 = 0; k2 < 16; ++k2) cnt += (tv[k2] == c) ? 1 : 0;
        int sc = cnt;
        #pragma unroll
        for (int d2 = 1; d2 < 64; d2 <<= 1) {
            int u = __shfl_up(sc, d2);
            if (l >= d2) sc += u;
        }
        if (l == 63) sm.wsum[w] = sc;
        __syncthreads();
        int woff = 0;
        if (w > 0) woff += sm.wsum[0];
        if (w > 1) woff += sm.wsum[1];
        if (w > 2) woff += sm.wsum[2];
        int off = woff + sc - cnt;
        #pragma unroll
        for (int k2 = 0; k2 < 16; ++k2) {
            if (tv[k2] == c) { if (off < LCAP) sm.idx[off] = rbase + k2; ++off; }
        }
        mtot = sm.wsum[0] + sm.wsum[1] + sm.wsum[2] + sm.wsum[3];
        if (t >= mtot && t < MAXM) sm.idx[t] = 0;    // pad: staging never reads garbage
    }
    mm  = mtot < MAXM ? mtot : MAXM;
    nfj = (mm + 15) >> 4;
    __syncthreads();

    const bool work = !(h == 1 && mm <= 64);
    if (work) {
        if (t < MAXM) {
            float s2 = 0.0f, q2 = 0.0f;
            if (t < mm) {
                const float* pp = P + (size_t)sm.idx[t] * PS;
                #pragma unroll 5
                for (int s = 0; s < 65; ++s) s2 += pp[s];
                q2 = sq[sm.idx[t]];
            }
            sm.rng[t] = s2;
            sm.sqg[t] = q2;
        }
        #pragma unroll
        for (int kk = 0; kk < 8; ++kk) {
            int q = w * 8 + kk;
            int row = q * 4 + (l >> 4);
            if (row < ((mm + 3) & ~3)) {
                int sc = (l & 15) ^ (row & 7);
                gload16(Xb + (size_t)sm.idx[row] * DIM + sc * 8, &sm.tX[q * 512]);
            }
        }
        __syncthreads();

        const int rowbase = h * 64 + w * 16;
        if (rowbase < mm) {
            f32x4 C[8] = {};
            const int arow = rowbase + lr;
            #pragma unroll
            for (int ks = 0; ks < 4; ++ks) {
                int cb = ks * 4 + lg;
                short8 a = *reinterpret_cast<const short8*>(&sm.tX[arow * DIM + ((cb ^ (arow & 7)) * 8)]);
                #pragma unroll
                for (int fj = 0; fj < 8; ++fj) {
                    if (fj < nfj) {
                        int brow = fj * 16 + lr;
                        short8 bb = *reinterpret_cast<const short8*>(&sm.tX[brow * DIM + ((cb ^ (brow & 7)) * 8)]);
                        C[fj] = __builtin_amdgcn_mfma_f32_16x16x32_bf16(a, bb, C[fj], 0, 0, 0);
                    }
                }
            }
            #pragma unroll
            for (int fj = 0; fj < 8; ++fj) {
                if (fj < nfj) {
                    int q = fj * 16 + lr;
                    #pragma unroll
                    for (int r = 0; r < 4; ++r) {
                        int p = rowbase + lg * 4 + r;
                        if (q < mm && p < q) {
                            float d2 = fmaxf(sm.sqg[p] + sm.sqg[q] - 2.0f * C[fj][r], 0.0f);
                            float dist = __builtin_amdgcn_sqrtf(d2);
                            float J = __logf(sm.rng[p] + sm.rng[q]) + dist;
                            if (J > 0.0f) csum += J * J;
                            cpairs += 1.0f;
                        }
                    }
                }
            }
        }

        if (h == 0 && mtot > MAXM) {     // fp32 fallback, practically unreachable
            int mq = mtot < LCAP ? mtot : LCAP;
            for (int q = MAXM; q < mq; ++q) {
                int rq = sm.idx[q];
                const float4* xb = reinterpret_cast<const float4*>(X + (size_t)rq * DIM);
                float sqq = sq[rq];
                float rnq = 0.0f;
                for (int s = 0; s < 65; ++s) rnq += P[(size_t)rq * PS + s];
                for (int p2 = t; p2 < q; p2 += 256) {
                    int rp = sm.idx[p2];
                    const float4* xa = reinterpret_cast<const float4*>(X + (size_t)rp * DIM);
                    float d = 0.0f;
                    for (int kq = 0; kq < 32; ++kq) {
                        float4 av = xa[kq], bv = xb[kq];
                        d += av.x * bv.x + av.y * bv.y + av.z * bv.z + av.w * bv.w;
                    }
                    float rnp = 0.0f;
                    for (int s = 0; s < 65; ++s) rnp += P[(size_t)rp * PS + s];
                    float d2 = fmaxf(sq[rp] + sqq - 2.0f * d, 0.0f);
                    float dist = __builtin_amdgcn_sqrtf(d2);
                    float J = __logf(rnp + rnq) + dist;
                    if (J > 0.0f) csum += J * J;
                    cpairs += 1.0f;
                }
            }
        }

        #pragma unroll
        for (int mr = 1; mr < 64; mr <<= 1) {
            csum   += __shfl_xor(csum, mr);
            cpairs += __shfl_xor(cpairs, mr);
        }
        if (l == 0) { sm.red[w] = csum; sm.red[8 + w] = cpairs; }
        __syncthreads();
        if (t == 0) {
            float bs = sm.red[0] + sm.red[1] + sm.red[2] + sm.red[3];
            float bc = sm.red[8] + sm.red[9] + sm.red[10] + sm.red[11];
            if (bs != 0.0f || bc != 0.0f) {
                atomicAdd(&acc[0], bs);
                atomicAdd(&acc[1], bc);
            }
        }
    }
}

union SMU { SRow r; SLoss l; };

// ======================= path A: single cooperative kernel =======================
__global__ __launch_bounds__(256, 3) void coop_kernel(
        const float* __restrict__ X, const int* __restrict__ tgt,
        unsigned short* __restrict__ Xb, float* __restrict__ sq,
        float* __restrict__ P, float* __restrict__ acc, float* __restrict__ out)
{
    __shared__ SMU sm;
    cg::grid_group grid = cg::this_grid();
    const int t = threadIdx.x;
    const int b = blockIdx.x;
    const int nblk = gridDim.x;

    // phase 0: prep (8 rows per block-iteration) + zero acc
    for (int row0 = b * 8; row0 < NROW; row0 += nblk * 8)
        prep_rows(X, Xb, sq, row0, t);
    if (b == 0 && t < 2) acc[t] = 0.0f;
    grid.sync();

    // phase 1: rowneg partials over 2080 triangular tiles, grid-stride
    for (int k = b; k < NTILE; k += nblk) {
        __syncthreads();                 // previous iteration's LDS readers done
        rowneg_tile(&sm, Xb, sq, tgt, P, k, t);
    }
    grid.sync();

    // phase 2: per-class loss on blocks 0..127
    if (b < 2 * NCLS)
        loss_body(&sm, Xb, X, sq, tgt, P, acc, b >> 1, b & 1, t);
    grid.sync();

    if (b == 0 && t == 0)
        out[0] = acc[0] / (2.0f * acc[1]);   // len_p = 2 * upper-tri count
}

// ======================= path B: proven 3-kernel fallback =======================
__global__ __launch_bounds__(256) void prep_kernel(const float* __restrict__ X,
        unsigned short* __restrict__ Xb, float* __restrict__ sq,
        float* __restrict__ acc, unsigned* __restrict__ tick)
{
    prep_rows(X, Xb, sq, blockIdx.x * 8, threadIdx.x);
    if (blockIdx.x == 0) {
        if (threadIdx.x == 64) { acc[0] = 0.0f; acc[1] = 0.0f; }
        if (threadIdx.x == 65) tick[0] = 0u;
    }
}

__global__ __launch_bounds__(256, 4) void rowneg_kernel(
        const unsigned short* __restrict__ Xb, const float* __restrict__ sq,
        const int* __restrict__ tgt, float* __restrict__ P)
{
    __shared__ SMU sm;
    rowneg_tile(&sm, Xb, sq, tgt, P, blockIdx.x, threadIdx.x);
}

__global__ __launch_bounds__(256) void loss_kernel(
        const unsigned short* __restrict__ Xb, const float* __restrict__ X,
        const float* __restrict__ sq, const int* __restrict__ tgt,
        const float* __restrict__ P,
        float* __restrict__ acc, unsigned* __restrict__ tick, float* __restrict__ out)
{
    __shared__ SMU sm;
    loss_body(&sm, Xb, X, sq, tgt, P, acc, blockIdx.x >> 1, blockIdx.x & 1, threadIdx.x);
    __threadfence();
    if (threadIdx.x == 0) {
        unsigned old = atomicAdd(tick, 1u);
        if (old == 2 * NCLS - 1) {
            float s  = atomicAdd(&acc[0], 0.0f);
            float n2 = atomicAdd(&acc[1], 0.0f);
            out[0] = s / (2.0f * n2);
        }
    }
}

extern "C" void kernel_launch(void* const* d_in, const int* in_sizes, int n_in,
                              void* d_out, int out_size, void* d_ws, size_t ws_size,
                              hipStream_t stream)
{
    const float* X  = (const float*)d_in[0];
    const int* tgt  = (const int*)d_in[1];
    float* out      = (float*)d_out;

    char* ws = (char*)d_ws;
    unsigned short* Xb = (unsigned short*)ws;                 // 1 MB bf16 copy
    float*    sq   = (float*)(ws + (size_t)NROW * DIM * 2);   // 16 KB
    float*    P    = sq + NROW;                               // ~1.06 MB write-only partials
    float*    acc  = P + (size_t)NROW * PS;                   // 2 floats
    unsigned* tick = (unsigned*)(acc + 2);                    // 1 uint (fallback only)

    // try single cooperative kernel (one dispatch, grid.sync between phases)
    int maxb = 0;
    hipError_t qe = hipOccupancyMaxActiveBlocksPerMultiprocessor(&maxb, coop_kernel, 256, 0);
    bool coop_ok = false;
    if (qe == hipSuccess && maxb >= 1) {
        int grid = 256 * maxb;
        if (grid > 1024) grid = 1024;
        if (grid < 2 * NCLS) grid = 2 * NCLS;
        void* args[] = {(void*)&X, (void*)&tgt, (void*)&Xb, (void*)&sq,
                        (void*)&P, (void*)&acc, (void*)&out};
        hipError_t le = hipLaunchCooperativeKernel((const void*)coop_kernel,
                                                   dim3(grid), dim3(256), args, 0, stream);
        coop_ok = (le == hipSuccess);
    }
    if (!coop_ok) {
        // proven 3-kernel pipeline (R10)
        prep_kernel<<<NROW / 8, 256, 0, stream>>>(X, Xb, sq, acc, tick);
        rowneg_kernel<<<NTILE, 256, 0, stream>>>(Xb, sq, tgt, P);
        loss_kernel<<<2 * NCLS, 256, 0, stream>>>(Xb, X, sq, tgt, P, acc, tick, out);
    }
}